// Round 5
// baseline (61.691 us; speedup 1.0000x reference)
//
#include <hip/hip_runtime.h>

// Problem constants (from reference): B=64, S=512, D=1024, fp32 in/out.
#define BS 64
#define SS 512
#define DD 1024
#define ROWS (BS * SS)          // 32768 output rows
#define ROWS_PER_WAVE 4
#define WAVES_PER_BLOCK 4
#define ROWS_PER_BLOCK (ROWS_PER_WAVE * WAVES_PER_BLOCK)   // 16
#define NBLOCKS (ROWS / ROWS_PER_BLOCK)                    // 2048

typedef float f4 __attribute__((ext_vector_type(4)));

// Kernel A: per batch row, compute packed segment bounds.
// bounds[b*SS + w] = lo | (len << 16). For w >= tot_words: lo=w, len=1
// (mean of a single row == passthrough, bit-exact with *1.0f).
__global__ __launch_bounds__(512) void bounds_kernel(
    const int* __restrict__ wid,        // [B, S] sorted, contiguous word ids
    unsigned int* __restrict__ bounds)  // [B, S]
{
    const int b = blockIdx.x;
    const int t = threadIdx.x;          // 512 threads = S
    const int* row = wid + b * SS;

    __shared__ int s_lo[SS + 1];
    __shared__ int s_tot;

    const int w_t  = row[t];
    const int prev = (t == 0) ? -1 : row[t - 1];
    if (t == SS - 1) { s_tot = w_t + 1; s_lo[w_t + 1] = SS; }
    if (w_t != prev) s_lo[w_t] = t;     // segment start
    __syncthreads();

    const int tot = s_tot;
    unsigned int val;
    if (t < tot) {
        const int lo  = s_lo[t];
        const int len = s_lo[t + 1] - lo;
        val = (unsigned int)lo | ((unsigned int)len << 16);
    } else {
        val = (unsigned int)t | (1u << 16);   // passthrough == 1-row mean
    }
    bounds[b * SS + t] = val;
}

// Kernel B: each wave owns ROWS_PER_WAVE full rows; no LDS, no syncthreads.
// Row = 4 KB = 4 quarter-rows of 64 lanes x float4.
__global__ __launch_bounds__(256) void merge_subword_kernel(
    const float* __restrict__ h,              // [B, S, D]
    const unsigned int* __restrict__ bounds,  // [B, S] packed lo|len<<16
    float* __restrict__ out)                  // [B, S, D]
{
    const int wave = (int)threadIdx.x >> 6;
    const int lane = (int)threadIdx.x & 63;
    const int row0 = (int)blockIdx.x * ROWS_PER_BLOCK + wave * ROWS_PER_WAVE;

    // One vector load fetches all 4 packed bounds; lanes 0..3 hold them.
    const unsigned int bd4 = bounds[row0 + (lane & 3)];

    #pragma unroll
    for (int k = 0; k < ROWS_PER_WAVE; ++k) {
        const unsigned int bd = (unsigned int)__builtin_amdgcn_readlane((int)bd4, k);
        const int r   = row0 + k;                 // global row index (b*SS + w)
        const int lo  = (int)(bd & 0xFFFFu);
        const int len = (int)(bd >> 16);
        const float inv = 1.0f / (float)len;

        // input rows start at batch base (r & ~(SS-1)) + lo
        const f4* bp = (const f4*)(h + ((size_t)((r & ~(SS - 1)) + lo) * DD));
        f4 a0 = (f4)(0.f), a1 = (f4)(0.f), a2 = (f4)(0.f), a3 = (f4)(0.f);
        for (int t = 0; t < len; ++t) {
            const f4* p = bp + (size_t)t * (DD / 4) + lane;
            a0 += p[0 * 64];
            a1 += p[1 * 64];
            a2 += p[2 * 64];
            a3 += p[3 * 64];
        }
        a0 *= inv; a1 *= inv; a2 *= inv; a3 *= inv;

        f4* dst = (f4*)(out + (size_t)r * DD) + lane;
        __builtin_nontemporal_store(a0, dst + 0 * 64);
        __builtin_nontemporal_store(a1, dst + 1 * 64);
        __builtin_nontemporal_store(a2, dst + 2 * 64);
        __builtin_nontemporal_store(a3, dst + 3 * 64);
    }
}

extern "C" void kernel_launch(void* const* d_in, const int* in_sizes, int n_in,
                              void* d_out, int out_size, void* d_ws, size_t ws_size,
                              hipStream_t stream) {
    (void)in_sizes; (void)n_in; (void)out_size; (void)ws_size;
    const float* h   = (const float*)d_in[0];
    const int*   wid = (const int*)d_in[1];
    float*       out = (float*)d_out;
    unsigned int* bounds = (unsigned int*)d_ws;   // needs B*S*4 = 128 KB

    bounds_kernel<<<dim3(BS), dim3(SS), 0, stream>>>(wid, bounds);
    merge_subword_kernel<<<dim3(NBLOCKS), dim3(256), 0, stream>>>(h, bounds, out);
}

// Round 6
// 53.048 us; speedup vs baseline: 1.1629x; 1.1629x over previous
//
#include <hip/hip_runtime.h>

// Problem constants (from reference): B=64, S=512, D=1024, fp32 in/out.
#define BS 64
#define SS 512
#define DD 1024
#define CH 8                       // tokens per wave-task chunk
#define NCHUNK (SS / CH)           // 64 chunks per batch row
#define QPT 4                      // quarter-rows per token row (1 KB each)
#define TASKS (BS * NCHUNK * QPT)  // 16384 wave-tasks
#define NBLOCKS (TASKS / 4)        // 4 waves per block -> 4096 blocks

typedef float f4 __attribute__((ext_vector_type(4)));

// Kernel A: per-token packed descriptor.
//   bit31        : position t >= tot_words  (passthrough output at position t)
//   bits 30..16  : segment length if a segment STARTS at token t, else 0
//   bits 15..0   : output word index w = wid[t] (valid when len field != 0)
__global__ __launch_bounds__(512) void desc_kernel(
    const int* __restrict__ wid,      // [B, S] sorted, contiguous word ids
    unsigned int* __restrict__ desc)  // [B, S]
{
    const int b = blockIdx.x;
    const int t = threadIdx.x;        // 512 threads = S
    const int* row = wid + b * SS;

    __shared__ int s_lo[SS + 1];
    __shared__ int s_tot;

    const int w_t  = row[t];
    const int prev = (t == 0) ? -1 : row[t - 1];
    if (t == SS - 1) { s_tot = w_t + 1; s_lo[w_t + 1] = SS; }
    if (w_t != prev) s_lo[w_t] = t;   // segment start
    __syncthreads();

    unsigned int v = 0;
    if (t >= s_tot) v |= 0x80000000u;
    if (w_t != prev) {                // segment starts at t (s_lo[w_t] == t)
        const int len = s_lo[w_t + 1] - t;
        v |= ((unsigned int)len << 16) | (unsigned int)w_t;
    }
    desc[b * SS + t] = v;
}

// Kernel B: one wave per (b, 8-token chunk, quarter). 8 independent prefetch
// loads up front; all combination register-local with compile-time indices.
__global__ __launch_bounds__(256) void merge_subword_kernel(
    const float* __restrict__ h,              // [B, S, D]
    const unsigned int* __restrict__ desc,    // [B, S]
    float* __restrict__ out)                  // [B, S, D]
{
    const int wave = (int)threadIdx.x >> 6;
    const int lane = (int)threadIdx.x & 63;
    const int task = (int)blockIdx.x * 4 + wave;

    const int q     = task & 3;                 // quarter-row
    const int tmp   = task >> 2;
    const int chunk = tmp & (NCHUNK - 1);
    const int b     = tmp >> 6;                 // NCHUNK = 64 -> 6 bits
    const int t0    = chunk * CH;

    const f4* hp = (const f4*)h;                // f4 units: row r -> r*256
    f4*       op = (f4*)out;
    const int rowbase = b * SS + t0;            // token-row index
    const int sl      = q * 64 + lane;          // slice offset within row (f4 units)

    // Descriptor for the 8 tokens (coalesced 32B, lanes repeat 8-wide).
    const unsigned int dvec = desc[rowbase + (lane & 7)];

    // 8 independent prefetch loads (compile-time indices only).
    f4 p[CH];
    #pragma unroll
    for (int i = 0; i < CH; ++i) p[i] = hp[(rowbase + i) * 256 + sl];

    #pragma unroll
    for (int i = 0; i < CH; ++i) {
        const unsigned int d =
            (unsigned int)__builtin_amdgcn_readlane((int)dvec, i);  // scalar
        if (d & 0x80000000u) {
            // passthrough: position t0+i keeps original values
            op[(rowbase + i) * 256 + sl] = p[i];
        }
        const int len = (int)((d >> 16) & 0x7FFFu);
        if (len) {                           // segment starts at token t0+i
            f4 acc = p[i];
            // in-chunk part: static indices, predicated on scalar len
            #pragma unroll
            for (int j = 1; j < CH - i; ++j)
                if (j < len) acc += p[i + j];
            // crossing part: uniform short loop (owner finishes the segment)
            for (int j = CH - i; j < len; ++j)
                acc += hp[(rowbase + i + j) * 256 + sl];
            const float inv = 1.0f / (float)len;   // len==1 -> exactly 1.0f
            acc *= inv;
            const int w = (int)(d & 0xFFFFu);
            op[(b * SS + w) * 256 + sl] = acc;
        }
    }
}

extern "C" void kernel_launch(void* const* d_in, const int* in_sizes, int n_in,
                              void* d_out, int out_size, void* d_ws, size_t ws_size,
                              hipStream_t stream) {
    (void)in_sizes; (void)n_in; (void)out_size; (void)ws_size;
    const float* h   = (const float*)d_in[0];
    const int*   wid = (const int*)d_in[1];
    float*       out = (float*)d_out;
    unsigned int* desc = (unsigned int*)d_ws;   // needs B*S*4 = 128 KB

    desc_kernel<<<dim3(BS), dim3(SS), 0, stream>>>(wid, desc);
    merge_subword_kernel<<<dim3(NBLOCKS), dim3(256), 0, stream>>>(h, desc, out);
}

// Round 7
// 52.707 us; speedup vs baseline: 1.1704x; 1.0065x over previous
//
#include <hip/hip_runtime.h>

// Problem constants (from reference): B=64, S=512, D=1024, fp32 in/out.
#define BS 64
#define SS 512
#define DD 1024
#define CH 8                       // tokens per wave-task chunk
#define NCHUNK (SS / CH)           // 64 chunks per batch row
#define QPT 4                      // quarter-rows per token row (1 KB each)
#define TASKS (BS * NCHUNK * QPT)  // 16384 wave-tasks
#define NTASK 4                    // tasks per wave (software-pipelined)
#define WAVES_TOTAL (TASKS / NTASK)        // 4096
#define NBLOCKS (WAVES_TOTAL / 4)          // 1024 blocks x 4 waves

typedef float f4 __attribute__((ext_vector_type(4)));

// Kernel A: per-token packed descriptor.
//   bit31        : position t >= tot_words  (passthrough output at position t)
//   bits 30..16  : segment length if a segment STARTS at token t, else 0
//   bits 15..0   : output word index w = wid[t] (valid when len field != 0)
__global__ __launch_bounds__(512) void desc_kernel(
    const int* __restrict__ wid,      // [B, S] sorted, contiguous word ids
    unsigned int* __restrict__ desc)  // [B, S]
{
    const int b = blockIdx.x;
    const int t = threadIdx.x;        // 512 threads = S
    const int* row = wid + b * SS;

    __shared__ int s_lo[SS + 1];
    __shared__ int s_tot;

    const int w_t  = row[t];
    const int prev = (t == 0) ? -1 : row[t - 1];
    if (t == SS - 1) { s_tot = w_t + 1; s_lo[w_t + 1] = SS; }
    if (w_t != prev) s_lo[w_t] = t;   // segment start
    __syncthreads();

    unsigned int v = 0;
    if (t >= s_tot) v |= 0x80000000u;
    if (w_t != prev) {                // segment starts at t (s_lo[w_t] == t)
        const int len = s_lo[w_t + 1] - t;
        v |= ((unsigned int)len << 16) | (unsigned int)w_t;
    }
    desc[b * SS + t] = v;
}

// Kernel B: 4 tasks per wave, 1-deep software pipeline with named buffers.
__global__ __launch_bounds__(256) void merge_subword_kernel(
    const float* __restrict__ h,              // [B, S, D]
    const unsigned int* __restrict__ desc,    // [B, S]
    float* __restrict__ out)                  // [B, S, D]
{
    const int wave = (int)threadIdx.x >> 6;
    const int lane = (int)threadIdx.x & 63;
    const int wg   = (int)blockIdx.x * 4 + wave;   // wave id in [0, WAVES_TOTAL)

    const f4* hp = (const f4*)h;                   // f4 units: row r -> r*256
    f4*       op = (f4*)out;

// Decode task -> (rowbase, slice, batch base row)
#define DECODE(task, rb, sl)                                   \
    {                                                          \
        const int q_    = (task) & 3;                          \
        const int tmp_  = (task) >> 2;                         \
        const int ch_   = tmp_ & (NCHUNK - 1);                 \
        const int b_    = tmp_ >> 6;                           \
        rb = b_ * SS + ch_ * CH;                               \
        sl = q_ * 64 + lane;                                   \
    }

// Issue loads for a task into named buffer (p, dv)
#define ISSUE(p, dv, rb, sl)                                   \
    {                                                          \
        dv = desc[(rb) + (lane & 7)];                          \
        _Pragma("unroll")                                      \
        for (int i = 0; i < CH; ++i)                           \
            p[i] = hp[((rb) + i) * 256 + (sl)];                \
    }

// Process a task from named buffer
#define PROCESS(p, dv, rb, sl)                                            \
    {                                                                     \
        const int batch_row0_ = (rb) & ~(SS - 1);                         \
        _Pragma("unroll")                                                 \
        for (int i = 0; i < CH; ++i) {                                    \
            const unsigned int d_ =                                       \
                (unsigned int)__builtin_amdgcn_readlane((int)(dv), i);    \
            if (d_ & 0x80000000u) {                                       \
                op[((rb) + i) * 256 + (sl)] = p[i];                       \
            }                                                             \
            const int len_ = (int)((d_ >> 16) & 0x7FFFu);                 \
            if (len_) {                                                   \
                f4 acc_ = p[i];                                           \
                _Pragma("unroll")                                         \
                for (int j = 1; j < CH - i; ++j)                          \
                    if (j < len_) acc_ += p[i + j];                       \
                for (int j = CH - i; j < len_; ++j)                       \
                    acc_ += hp[((rb) + i + j) * 256 + (sl)];              \
                acc_ *= (1.0f / (float)len_);                             \
                const int w_ = (int)(d_ & 0xFFFFu);                       \
                op[(batch_row0_ + w_) * 256 + (sl)] = acc_;               \
            }                                                             \
        }                                                                 \
    }

    f4 pA[CH], pB[CH];
    unsigned int dA, dB;
    int rbA, slA, rbB, slB;

    // it 0 issue
    DECODE(wg, rbA, slA);
    ISSUE(pA, dA, rbA, slA);

    // it 0 process / it 1 issue
    DECODE(wg + WAVES_TOTAL, rbB, slB);
    ISSUE(pB, dB, rbB, slB);
    PROCESS(pA, dA, rbA, slA);

    // it 1 process / it 2 issue
    DECODE(wg + 2 * WAVES_TOTAL, rbA, slA);
    ISSUE(pA, dA, rbA, slA);
    PROCESS(pB, dB, rbB, slB);

    // it 2 process / it 3 issue
    DECODE(wg + 3 * WAVES_TOTAL, rbB, slB);
    ISSUE(pB, dB, rbB, slB);
    PROCESS(pA, dA, rbA, slA);

    // it 3 process
    PROCESS(pB, dB, rbB, slB);

#undef DECODE
#undef ISSUE
#undef PROCESS
}

extern "C" void kernel_launch(void* const* d_in, const int* in_sizes, int n_in,
                              void* d_out, int out_size, void* d_ws, size_t ws_size,
                              hipStream_t stream) {
    (void)in_sizes; (void)n_in; (void)out_size; (void)ws_size;
    const float* h   = (const float*)d_in[0];
    const int*   wid = (const int*)d_in[1];
    float*       out = (float*)d_out;
    unsigned int* desc = (unsigned int*)d_ws;   // needs B*S*4 = 128 KB

    desc_kernel<<<dim3(BS), dim3(SS), 0, stream>>>(wid, desc);
    merge_subword_kernel<<<dim3(NBLOCKS), dim3(256), 0, stream>>>(h, desc, out);
}

// Round 8
// 48.547 us; speedup vs baseline: 1.2708x; 1.0857x over previous
//
#include <hip/hip_runtime.h>

// Problem constants (from reference): B=64, S=512, D=1024, fp32 in/out.
#define BS 64
#define SS 512
#define DD 1024
#define CH 8                       // tokens per wave-task chunk
#define NCHUNK (SS / CH)           // 64 chunks per batch row
#define QPT 4                      // quarter-rows per token row (1 KB each)
#define TASKS (BS * NCHUNK * QPT)  // 16384 wave-tasks
#define NBLOCKS (TASKS / 4)        // 4 waves per block -> 4096 blocks

typedef float f4 __attribute__((ext_vector_type(4)));

// Fully fused: each wave derives segment structure for its 8-token chunk from
// a 64-int wid window (ballot change-mask), then merges. Single kernel.
__global__ __launch_bounds__(256) void merge_subword_kernel(
    const float* __restrict__ h,     // [B, S, D]
    const int*   __restrict__ wid,   // [B, S] sorted, contiguous word ids
    float*       __restrict__ out)   // [B, S, D]
{
    const int wave = (int)threadIdx.x >> 6;
    const int lane = (int)threadIdx.x & 63;
    const int task = (int)blockIdx.x * 4 + wave;

    const int q     = task & 3;                 // quarter-row
    const int tmp   = task >> 2;
    const int chunk = tmp & (NCHUNK - 1);
    const int b     = tmp >> 6;                 // NCHUNK = 64 -> 6 bits
    const int t0    = chunk * CH;

    const f4* hp = (const f4*)h;                // f4 units: row r -> r*256
    f4*       op = (f4*)out;
    const int browbase = b * SS;                // batch base row
    const int rowbase  = browbase + t0;         // first token row of chunk
    const int sl       = q * 64 + lane;         // slice offset (f4 units)

    // --- wid window: lanes load wid[t0 .. t0+63]; past row end -> unique
    // sentinels so every out-of-row position registers as a "change".
    const int idx = t0 + lane;
    int v = (idx < SS) ? wid[browbase + idx] : -(2 + lane);

    // Uniform scalars: value before the chunk, total word count.
    const int wprev = (t0 == 0) ? -1 : wid[browbase + t0 - 1];
    const int tot   = wid[browbase + SS - 1] + 1;

    // --- 8 independent prefetch loads (compile-time indices only).
    f4 p[CH];
    #pragma unroll
    for (int i = 0; i < CH; ++i) p[i] = hp[(rowbase + i) * 256 + sl];

    // --- change mask: bit l set iff a new segment starts at token t0+l.
    int vp = __shfl_up(v, 1);
    const bool changed = (lane == 0) ? (v != wprev) : (v != vp);
    const unsigned long long M = __ballot(changed);   // wave-uniform (SGPR)

    #pragma unroll
    for (int i = 0; i < CH; ++i) {
        // tail passthrough: output position t0+i keeps original values
        if (t0 + i >= tot) {
            op[(rowbase + i) * 256 + sl] = p[i];
        }
        if ((M >> i) & 1ull) {                  // segment starts at token t0+i
            const int w = __builtin_amdgcn_readlane(v, i);  // wid[t0+i]
            const unsigned long long rest = M >> (i + 1);
            const int len = rest ? __ffsll((unsigned long long)rest) : 0;
            f4 acc = p[i];
            if (len) {                          // len in [1, 63-i]
                #pragma unroll
                for (int j = 1; j < CH - i; ++j)
                    if (j < len) acc += p[i + j];
                for (int j = CH - i; j < len; ++j)
                    acc += hp[(rowbase + i + j) * 256 + sl];
                acc *= (1.0f / (float)len);     // len==1 -> exactly 1.0f
                op[(browbase + w) * 256 + sl] = acc;
            } else {
                // segment extends past the 64-token window (essentially
                // never for this distribution; kept for correctness).
                #pragma unroll
                for (int j = 1; j < CH - i; ++j) acc += p[i + j];
                int cnt = CH - i;
                int tt = t0 + CH;
                while (tt < SS && wid[browbase + tt] == w) {
                    acc += hp[(browbase + tt) * 256 + sl];
                    ++cnt; ++tt;
                }
                acc *= (1.0f / (float)cnt);
                op[(browbase + w) * 256 + sl] = acc;
            }
        }
    }
}

extern "C" void kernel_launch(void* const* d_in, const int* in_sizes, int n_in,
                              void* d_out, int out_size, void* d_ws, size_t ws_size,
                              hipStream_t stream) {
    (void)in_sizes; (void)n_in; (void)out_size; (void)d_ws; (void)ws_size;
    const float* h   = (const float*)d_in[0];
    const int*   wid = (const int*)d_in[1];
    float*       out = (float*)d_out;

    merge_subword_kernel<<<dim3(NBLOCKS), dim3(256), 0, stream>>>(h, wid, out);
}

// Round 9
// 48.445 us; speedup vs baseline: 1.2734x; 1.0021x over previous
//
#include <hip/hip_runtime.h>

// Problem constants (from reference): B=64, S=512, D=1024, fp32 in/out.
#define BS 64
#define SS 512
#define DD 1024
#define CH 16                      // tokens per wave-task chunk
#define NCHUNK (SS / CH)           // 32 chunks per batch row
#define QPT 4                      // quarter-rows per token row (1 KB each)
#define TASKS (BS * NCHUNK * QPT)  // 8192 wave-tasks
#define NBLOCKS (TASKS / 4)        // 4 waves per block -> 2048 blocks

typedef float f4 __attribute__((ext_vector_type(4)));

// Fully fused: each wave derives segment structure for its 16-token chunk from
// a 64-int wid window (ballot change-mask), then merges. Single kernel.
// Output stores are nontemporal: output is write-once, never re-read -> keep
// LLC capacity for the input stream.
__global__ __launch_bounds__(256) void merge_subword_kernel(
    const float* __restrict__ h,     // [B, S, D]
    const int*   __restrict__ wid,   // [B, S] sorted, contiguous word ids
    float*       __restrict__ out)   // [B, S, D]
{
    const int wave = (int)threadIdx.x >> 6;
    const int lane = (int)threadIdx.x & 63;
    const int task = (int)blockIdx.x * 4 + wave;

    const int q     = task & 3;                 // quarter-row
    const int tmp   = task >> 2;
    const int chunk = tmp & (NCHUNK - 1);
    const int b     = tmp >> 5;                 // NCHUNK = 32 -> 5 bits
    const int t0    = chunk * CH;

    const f4* hp = (const f4*)h;                // f4 units: row r -> r*256
    f4*       op = (f4*)out;
    const int browbase = b * SS;                // batch base row
    const int rowbase  = browbase + t0;         // first token row of chunk
    const int sl       = q * 64 + lane;         // slice offset (f4 units)

    // --- wid window: lanes load wid[t0 .. t0+63]; past row end -> unique
    // sentinels so every out-of-row position registers as a "change".
    const int idx = t0 + lane;
    int v = (idx < SS) ? wid[browbase + idx] : -(2 + lane);

    // Uniform scalars: value before the chunk, total word count.
    const int wprev = (t0 == 0) ? -1 : wid[browbase + t0 - 1];
    const int tot   = wid[browbase + SS - 1] + 1;

    // --- 16 independent prefetch loads (compile-time indices only).
    f4 p[CH];
    #pragma unroll
    for (int i = 0; i < CH; ++i) p[i] = hp[(rowbase + i) * 256 + sl];

    // --- change mask: bit l set iff a new segment starts at token t0+l.
    int vp = __shfl_up(v, 1);
    const bool changed = (lane == 0) ? (v != wprev) : (v != vp);
    const unsigned long long M = __ballot(changed);   // wave-uniform (SGPR)

    #pragma unroll
    for (int i = 0; i < CH; ++i) {
        // tail passthrough: output position t0+i keeps original values
        if (t0 + i >= tot) {
            __builtin_nontemporal_store(p[i], &op[(rowbase + i) * 256 + sl]);
        }
        if ((M >> i) & 1ull) {                  // segment starts at token t0+i
            const int w = __builtin_amdgcn_readlane(v, i);  // wid[t0+i]
            const unsigned long long rest = M >> (i + 1);
            const int len = rest ? __ffsll((unsigned long long)rest) : 0;
            f4 acc = p[i];
            if (len) {                          // len in [1, 63-i]
                #pragma unroll
                for (int j = 1; j < CH - i; ++j)
                    if (j < len) acc += p[i + j];
                for (int j = CH - i; j < len; ++j)
                    acc += hp[(rowbase + i + j) * 256 + sl];
                acc *= (1.0f / (float)len);     // len==1 -> exactly 1.0f
                __builtin_nontemporal_store(acc, &op[(browbase + w) * 256 + sl]);
            } else {
                // segment extends past the 64-token window (essentially
                // never for this distribution; kept for correctness).
                #pragma unroll
                for (int j = 1; j < CH - i; ++j) acc += p[i + j];
                int cnt = CH - i;
                int tt = t0 + CH;
                while (tt < SS && wid[browbase + tt] == w) {
                    acc += hp[(browbase + tt) * 256 + sl];
                    ++cnt; ++tt;
                }
                acc *= (1.0f / (float)cnt);
                __builtin_nontemporal_store(acc, &op[(browbase + w) * 256 + sl]);
            }
        }
    }
}

extern "C" void kernel_launch(void* const* d_in, const int* in_sizes, int n_in,
                              void* d_out, int out_size, void* d_ws, size_t ws_size,
                              hipStream_t stream) {
    (void)in_sizes; (void)n_in; (void)out_size; (void)d_ws; (void)ws_size;
    const float* h   = (const float*)d_in[0];
    const int*   wid = (const int*)d_in[1];
    float*       out = (float*)d_out;

    merge_subword_kernel<<<dim3(NBLOCKS), dim3(256), 0, stream>>>(h, wid, out);
}